// Round 11
// baseline (167.734 us; speedup 1.0000x reference)
//
#include <hip/hip_runtime.h>

#define NB_MAX   1568   // buckets: ceil(100000/64)=1563, padded
#define CAP      1024   // fixed per-bucket record capacity (mean 768, +9σ safe)
#define BT_EDGES 4096   // edges per build tile
#define BT_TPB   512
#define EPE      8      // edges per thread in build (4096/512)

typedef __attribute__((ext_vector_type(4))) float floatx4;
typedef __attribute__((ext_vector_type(8))) short bf16x8;

__device__ __forceinline__ unsigned short f32_to_bf16(float f) {
  unsigned u = __float_as_uint(f);
  u = (u + 0x7fffu + ((u >> 16) & 1u)) >> 16;  // RNE
  return (unsigned short)u;
}
__device__ __forceinline__ float bf16lo(unsigned u) {
  return __uint_as_float(u << 16);
}
__device__ __forceinline__ float bf16hi(unsigned u) {
  return __uint_as_float(u & 0xffff0000u);
}
__device__ __forceinline__ unsigned pack2(float a, float b) {
  return (unsigned)f32_to_bf16(a) | ((unsigned)f32_to_bf16(b) << 16);
}
__device__ __forceinline__ bf16x8 zero_bf16x8() {
  bf16x8 v;
#pragma unroll
  for (int i = 0; i < 8; ++i) v[i] = 0;
  return v;
}

// ---------------------------------------------------------------------------
// Single-pass build (v3).  Changes vs round 10:
//  * streaming tail work (featb conversion, Wb pack) moved to the FRONT so
//    its load/store queue overlaps the barrier ladder and there is no
//    serial tail after pass 3;
//  * pass-2 operands (src, ew*em) prefetched during pass 1 into registers —
//    the scan + global-reserve round trip hides them; pass 2 is pure LDS.
// ---------------------------------------------------------------------------
__global__ __launch_bounds__(BT_TPB) void k_build(
    const float* __restrict__ feat, const int* __restrict__ src,
    const int* __restrict__ dst, const float* __restrict__ ew,
    const float* __restrict__ em, const float* __restrict__ Ws,
    const float* __restrict__ Wn, int* __restrict__ gCursor,
    uint2* __restrict__ recs, unsigned short* __restrict__ featb,
    unsigned short* __restrict__ Wb, int E, int nChunks, int nB) {
  __shared__ unsigned stageA[BT_EDGES];        // src | dL<<17   (16 KB)
  __shared__ unsigned short stageW[BT_EDGES];  // fix16 weight   (8 KB)
  __shared__ int A[NB_MAX];                    // loff -> writebase-loff
  __shared__ int B[NB_MAX];                    // cnt -> cursor -> ends
  __shared__ int waveSums[8];

  const int t = threadIdx.x;
  const int lane = t & 63;
  const int wvid = t >> 6;
  const int e0 = blockIdx.x * BT_EDGES;
  const int eEnd = min(e0 + BT_EDGES, E);
  const int nLocal = eEnd - e0;

  // streaming work first: feat -> bf16 (grid-stride) — queues deep, overlaps
  // the latency-bound sort phases below across the wave pool
  for (int c = blockIdx.x * BT_TPB + t; c < nChunks; c += gridDim.x * BT_TPB) {
    const float4* fp = reinterpret_cast<const float4*>(feat) + (size_t)c * 2;
    float4 a = fp[0], b = fp[1];
    uint4 o;
    o.x = pack2(a.x, a.y);
    o.y = pack2(a.z, a.w);
    o.z = pack2(b.x, b.y);
    o.w = pack2(b.z, b.w);
    reinterpret_cast<uint4*>(featb)[c] = o;
  }
  // W -> bf16 j-major block (block 0 only)
  if (blockIdx.x == 0) {
    for (int i = t; i < 1024; i += BT_TPB) {
      int j = i >> 4, c4 = i & 15;
      float4 w4 = reinterpret_cast<const float4*>(Ws)[i];
      float4 n4 = reinterpret_cast<const float4*>(Wn)[i];
      *reinterpret_cast<uint2*>(&Wb[j * 128 + c4 * 4]) =
          make_uint2(pack2(w4.x, w4.y), pack2(w4.z, w4.w));
      *reinterpret_cast<uint2*>(&Wb[j * 128 + 64 + c4 * 4]) =
          make_uint2(pack2(n4.x, n4.y), pack2(n4.z, n4.w));
    }
  }

  for (int i = t; i < NB_MAX; i += BT_TPB) B[i] = 0;
  __syncthreads();

  // pass 1: local histogram; prefetch ALL pass-2 operands into registers
  int dreg[EPE];
  unsigned xreg[EPE];
  unsigned short wreg[EPE];
#pragma unroll
  for (int k = 0; k < EPE; ++k) {
    int i = e0 + k * BT_TPB + t;
    dreg[k] = -1;
    if (i < eEnd) {
      int d = dst[i];
      dreg[k] = d;
      atomicAdd(&B[d >> 6], 1);
      xreg[k] = (unsigned)src[i] | ((unsigned)(d & 63) << 17);
      float w = ew[i] * em[i];
      int wf = (int)(w * 65535.0f + 0.5f);
      wreg[k] = (unsigned short)min(wf, 65535);
    }
  }
  __syncthreads();

  // exclusive scan of B -> A via wave shuffles (EPT=4, 512*4=2048 >= NB_MAX)
  {
    const int EPT = 4;
    int b0 = t * EPT;
    int v[EPT];
    int sum = 0;
#pragma unroll
    for (int j = 0; j < EPT; ++j) {
      v[j] = (b0 + j < nB) ? B[b0 + j] : 0;
      sum += v[j];
    }
    int x = sum;
#pragma unroll
    for (int d = 1; d < 64; d <<= 1) {
      int y = __shfl_up(x, d, 64);
      if (lane >= d) x += y;
    }
    if (lane == 63) waveSums[wvid] = x;
    __syncthreads();
    int wprefix = 0;
    for (int i = 0; i < wvid; ++i) wprefix += waveSums[i];
    int run = wprefix + x - sum;  // exclusive base for this thread
#pragma unroll
    for (int j = 0; j < EPT; ++j) {
      if (b0 + j < nB) A[b0 + j] = run;
      run += v[j];
    }
  }
  __syncthreads();

  // reserve global ranges; B becomes staging cursor, A becomes write delta
  for (int i = t; i < nB; i += BT_TPB) {
    int c = B[i];
    int l = A[i];
    int g = c ? atomicAdd(&gCursor[i], c) : 0;
    A[i] = i * CAP + g - l;
    B[i] = l;
  }
  __syncthreads();

  // pass 2: stage records bucket-sorted (pure LDS — operands in registers)
#pragma unroll
  for (int k = 0; k < EPE; ++k) {
    if (dreg[k] >= 0) {
      int r = atomicAdd(&B[dreg[k] >> 6], 1);
      stageA[r] = xreg[k];
      stageW[r] = wreg[k];
    }
  }
  __syncthreads();
  // B[j] now = loff[j+1]: monotone bucket END positions.

  // pass 3: coalesced write-out; bucket of i via binary search in LDS
  for (int i = t; i < nLocal; i += BT_TPB) {
    int lo = 0, hi = nB;
    while (lo < hi) {
      int mid = (lo + hi) >> 1;
      if (B[mid] > i) hi = mid; else lo = mid + 1;
    }
    int pos = A[lo] + i;
    if (pos < (lo + 1) * CAP)  // capacity guard (never fires statistically)
      recs[pos] = make_uint2(stageA[i], (unsigned)stageW[i]);
  }
}

// ---------------------------------------------------------------------------
// Fused gather + dual-linear.  Block = bucket = 64 dst nodes.
//   1. counting-sort the bucket's records by local node in LDS
//   2. per-node register-accumulation gather, DEPTH-2 SOFTWARE PIPELINE:
//      edge j+2's record + feat loads issue while edge j accumulates
//   3. MFMA: A self-half direct from global featb, B direct from global Wb,
//      neigh-half from An.   LDS = 18.2 KB.
// ---------------------------------------------------------------------------
__global__ __launch_bounds__(256) void sage_gather_gemm(
    const unsigned short* __restrict__ featb,
    const unsigned short* __restrict__ Wb, const int* __restrict__ gCursor,
    const uint2* __restrict__ recs, const float* __restrict__ bs,
    const float* __restrict__ bn, float* __restrict__ out, int N) {
  __shared__ unsigned short An[64][72];  // h_neigh only; stride 72 (144 B)
  __shared__ uint2 recsL[CAP];
  __shared__ int cntS[64], offS[64], curS[64];

  const int t = threadIdx.x;
  const int b = blockIdx.x;
  const int n0 = b * 64;
  const int base = b * CAP;
  const int cb = min(gCursor[b], CAP);

  if (t < 64) cntS[t] = 0;
  __syncthreads();

  // histogram by local node
  for (int i = t; i < cb; i += 256)
    atomicAdd(&cntS[(recs[base + i].x >> 17) & 63], 1);
  __syncthreads();

  // exclusive scan of 64 counters: single wave-0 shuffle scan
  if (t < 64) {
    int c = cntS[t];
    int x = c;
#pragma unroll
    for (int d = 1; d < 64; d <<= 1) {
      int y = __shfl_up(x, d, 64);
      if (t >= d) x += y;
    }
    offS[t] = x - c;
    curS[t] = x - c;
  }
  __syncthreads();

  // scatter records into node-sorted LDS order
  for (int i = t; i < cb; i += 256) {
    uint2 rec = recs[base + i];
    int r = atomicAdd(&curS[(rec.x >> 17) & 63], 1);
    recsL[r] = rec;
  }
  __syncthreads();

  // per-node gather: 4 lanes/node, register accumulation, depth-2 pipeline
  {
    int nl = t >> 2, q = t & 3;
    int deg = cntS[nl], off = offS[nl];
    float acc[16];
#pragma unroll
    for (int i = 0; i < 16; ++i) acc[i] = 0.f;
    const uint4* fb = reinterpret_cast<const uint4*>(featb);

    uint4 c0, c1, p0, p1;
    float cw = 0.f, pw = 0.f;
    if (deg > 0) {
      uint2 r0 = recsL[off];
      const uint4* f0 = fb + (size_t)(r0.x & 0x1FFFF) * 8 + q * 2;
      c0 = f0[0]; c1 = f0[1];
      cw = (float)r0.y * (1.0f / 65535.0f);
    }
    if (deg > 1) {
      uint2 r1 = recsL[off + 1];
      const uint4* f1 = fb + (size_t)(r1.x & 0x1FFFF) * 8 + q * 2;
      p0 = f1[0]; p1 = f1[1];
      pw = (float)r1.y * (1.0f / 65535.0f);
    }
    for (int j = 0; j < deg; ++j) {
      uint4 u0 = c0, u1 = c1;
      float w = cw;
      c0 = p0; c1 = p1; cw = pw;
      if (j + 2 < deg) {
        uint2 rn = recsL[off + j + 2];
        const uint4* fn = fb + (size_t)(rn.x & 0x1FFFF) * 8 + q * 2;
        p0 = fn[0]; p1 = fn[1];
        pw = (float)rn.y * (1.0f / 65535.0f);
      }
      acc[0]  += w * bf16lo(u0.x); acc[1]  += w * bf16hi(u0.x);
      acc[2]  += w * bf16lo(u0.y); acc[3]  += w * bf16hi(u0.y);
      acc[4]  += w * bf16lo(u0.z); acc[5]  += w * bf16hi(u0.z);
      acc[6]  += w * bf16lo(u0.w); acc[7]  += w * bf16hi(u0.w);
      acc[8]  += w * bf16lo(u1.x); acc[9]  += w * bf16hi(u1.x);
      acc[10] += w * bf16lo(u1.y); acc[11] += w * bf16hi(u1.y);
      acc[12] += w * bf16lo(u1.z); acc[13] += w * bf16hi(u1.z);
      acc[14] += w * bf16lo(u1.w); acc[15] += w * bf16hi(u1.w);
    }
    float inv = 1.0f / fmaxf((float)deg, 1.0f);
    uint4 o0, o1;
    o0.x = pack2(acc[0] * inv, acc[1] * inv);
    o0.y = pack2(acc[2] * inv, acc[3] * inv);
    o0.z = pack2(acc[4] * inv, acc[5] * inv);
    o0.w = pack2(acc[6] * inv, acc[7] * inv);
    o1.x = pack2(acc[8] * inv, acc[9] * inv);
    o1.y = pack2(acc[10] * inv, acc[11] * inv);
    o1.z = pack2(acc[12] * inv, acc[13] * inv);
    o1.w = pack2(acc[14] * inv, acc[15] * inv);
    *reinterpret_cast<uint4*>(&An[nl][q * 16]) = o0;
    *reinterpret_cast<uint4*>(&An[nl][q * 16 + 8]) = o1;
  }
  __syncthreads();

  // MFMA phase (round-4-validated mapping)
  const int wv = t >> 6;
  const int ln = t & 63;
  const int col = ln & 15;
  const int quad = ln >> 4;
  const int gn = n0 + wv * 16 + col;

  floatx4 acc4[4];
#pragma unroll
  for (int jt = 0; jt < 4; ++jt) {
    float bb = bs[jt * 16 + col] + bn[jt * 16 + col];
    acc4[jt] = (floatx4){bb, bb, bb, bb};
  }

#pragma unroll
  for (int kk = 0; kk < 4; ++kk) {
    bf16x8 af;
    if (kk < 2) {
      if (gn < N) {
        af = *reinterpret_cast<const bf16x8*>(featb + (size_t)gn * 64 + kk * 32 + quad * 8);
      } else {
        af = zero_bf16x8();
      }
    } else {
      af = *reinterpret_cast<const bf16x8*>(&An[wv * 16 + col][(kk - 2) * 32 + quad * 8]);
    }
#pragma unroll
    for (int jt = 0; jt < 4; ++jt) {
      bf16x8 bf = *reinterpret_cast<const bf16x8*>(
          Wb + (jt * 16 + col) * 128 + kk * 32 + quad * 8);
      acc4[jt] = __builtin_amdgcn_mfma_f32_16x16x32_bf16(af, bf, acc4[jt], 0, 0, 0);
    }
  }

#pragma unroll
  for (int jt = 0; jt < 4; ++jt) {
#pragma unroll
    for (int r = 0; r < 4; ++r) {
      int m = quad * 4 + r;
      int g = n0 + wv * 16 + m;
      if (g < N) out[(size_t)g * 64 + jt * 16 + col] = acc4[jt][r];
    }
  }
}

extern "C" void kernel_launch(void* const* d_in, const int* in_sizes, int n_in,
                              void* d_out, int out_size, void* d_ws, size_t ws_size,
                              hipStream_t stream) {
  const float* feat = (const float*)d_in[0];
  const int*   src  = (const int*)d_in[1];
  const int*   dst  = (const int*)d_in[2];
  const float* ew   = (const float*)d_in[3];
  const float* em   = (const float*)d_in[4];
  const float* Ws   = (const float*)d_in[5];
  const float* bs   = (const float*)d_in[6];
  const float* Wn   = (const float*)d_in[7];
  const float* bn   = (const float*)d_in[8];
  float* out = (float*)d_out;

  const int N = in_sizes[0] / 64;  // 100000
  const int E = in_sizes[1];       // 1200000
  const int nB = (N + 63) / 64;    // 1563

  // Workspace: featb 12.8MB | Wb 16KB | recs 12.85MB | gCursor 6.3KB ~ 25.7MB
  unsigned short* featb = (unsigned short*)d_ws;
  unsigned short* Wb    = featb + (size_t)N * 64;
  uint2* recs    = (uint2*)(Wb + 64 * 128);
  int*   gCursor = (int*)(recs + (size_t)NB_MAX * CAP);

  hipMemsetAsync(gCursor, 0, NB_MAX * sizeof(int), stream);

  int nChunks = N * 8;  // 8-float conversion chunks
  int gB = (E + BT_EDGES - 1) / BT_EDGES;  // 293

  k_build<<<gB, BT_TPB, 0, stream>>>(feat, src, dst, ew, em, Ws, Wn,
                                     gCursor, recs, featb, Wb, E, nChunks, nB);
  sage_gather_gemm<<<nB, 256, 0, stream>>>(featb, Wb, gCursor, recs,
                                           bs, bn, out, N);
}

// Round 12
// 163.849 us; speedup vs baseline: 1.0237x; 1.0237x over previous
//
#include <hip/hip_runtime.h>

#define NB_MAX   1568   // buckets: ceil(100000/64)=1563, padded
#define CAP      1024   // fixed per-bucket record capacity (mean 768, +9σ safe)
#define BT_EDGES 4096   // edges per build tile
#define BT_TPB   512
#define EPE      8      // edges per thread in build (4096/512)

typedef __attribute__((ext_vector_type(4))) float floatx4;
typedef __attribute__((ext_vector_type(2))) float floatx2;
typedef __attribute__((ext_vector_type(8))) short bf16x8;

__device__ __forceinline__ unsigned short f32_to_bf16(float f) {
  unsigned u = __float_as_uint(f);
  u = (u + 0x7fffu + ((u >> 16) & 1u)) >> 16;  // RNE
  return (unsigned short)u;
}
__device__ __forceinline__ unsigned pack2(float a, float b) {
  return (unsigned)f32_to_bf16(a) | ((unsigned)f32_to_bf16(b) << 16);
}
__device__ __forceinline__ bf16x8 zero_bf16x8() {
  bf16x8 v;
#pragma unroll
  for (int i = 0; i < 8; ++i) v[i] = 0;
  return v;
}

// ---- fp8 e4m3fn helpers (HW path on gfx950; software fallback) ------------
#if __has_builtin(__builtin_amdgcn_cvt_pk_fp8_f32)
__device__ __forceinline__ unsigned pack_fp8x4(float a, float b, float c, float d) {
  unsigned v = (unsigned)__builtin_amdgcn_cvt_pk_fp8_f32(a, b, 0, false);
  v = (unsigned)__builtin_amdgcn_cvt_pk_fp8_f32(c, d, (int)v, true);
  return v;
}
#else
__device__ __forceinline__ unsigned sw_f32_fp8(float f) {
  unsigned u = __float_as_uint(f);
  unsigned s = (u >> 24) & 0x80u;
  unsigned au = u & 0x7fffffffu;
  if (au > 0x43E00000u) au = 0x43E00000u;      // clamp to 448
  au += 0x7FFFFu + ((au >> 20) & 1u);          // RNE at bit 20
  int e = (int)(au >> 23) - 120;               // fp8 exponent
  if (e <= 0) return s;                        // flush underflow to ±0
  return s | ((unsigned)e << 3) | ((au >> 20) & 7u);
}
__device__ __forceinline__ unsigned pack_fp8x4(float a, float b, float c, float d) {
  return sw_f32_fp8(a) | (sw_f32_fp8(b) << 8) | (sw_f32_fp8(c) << 16) |
         (sw_f32_fp8(d) << 24);
}
#endif

#if __has_builtin(__builtin_amdgcn_cvt_pk_f32_fp8)
__device__ __forceinline__ void dec4(float* acc, unsigned w32, float wt) {
  floatx2 f0 = __builtin_amdgcn_cvt_pk_f32_fp8((int)w32, false);
  floatx2 f1 = __builtin_amdgcn_cvt_pk_f32_fp8((int)w32, true);
  acc[0] += wt * f0.x; acc[1] += wt * f0.y;
  acc[2] += wt * f1.x; acc[3] += wt * f1.y;
}
#else
__device__ __forceinline__ float sw_fp8_f32(unsigned b) {
  unsigned s = (b & 0x80u) << 24;
  unsigned e = (b >> 3) & 0xFu;
  unsigned m = b & 7u;
  float fn = __uint_as_float(s | ((e + 120u) << 23) | (m << 20));
  float fd = (float)(int)m * 0.001953125f;      // 2^-9
  fd = (b & 0x80u) ? -fd : fd;
  return e ? fn : fd;
}
__device__ __forceinline__ void dec4(float* acc, unsigned w32, float wt) {
  acc[0] += wt * sw_fp8_f32(w32 & 0xFF);
  acc[1] += wt * sw_fp8_f32((w32 >> 8) & 0xFF);
  acc[2] += wt * sw_fp8_f32((w32 >> 16) & 0xFF);
  acc[3] += wt * sw_fp8_f32(w32 >> 24);
}
#endif

// ---------------------------------------------------------------------------
// Single-pass build (r10 structure + rec32 + fp8 conversion).
// Record (32-bit): src(0..16) | dL(17..22) | w9(23..31).
// ---------------------------------------------------------------------------
__global__ __launch_bounds__(BT_TPB) void k_build(
    const float* __restrict__ feat, const int* __restrict__ src,
    const int* __restrict__ dst, const float* __restrict__ ew,
    const float* __restrict__ em, const float* __restrict__ Ws,
    const float* __restrict__ Wn, int* __restrict__ gCursor,
    unsigned* __restrict__ recs, unsigned short* __restrict__ featb,
    unsigned char* __restrict__ featq, unsigned short* __restrict__ Wb,
    int E, int nChunks, int nB) {
  __shared__ unsigned stage[BT_EDGES];  // 16 KB: bucket-sorted rec32
  __shared__ int A[NB_MAX];             // loff -> writebase-loff
  __shared__ int B[NB_MAX];             // cnt -> cursor -> ends
  __shared__ int waveSums[8];

  const int t = threadIdx.x;
  const int lane = t & 63;
  const int wvid = t >> 6;
  const int e0 = blockIdx.x * BT_EDGES;
  const int eEnd = min(e0 + BT_EDGES, E);
  const int nLocal = eEnd - e0;

  for (int i = t; i < NB_MAX; i += BT_TPB) B[i] = 0;
  __syncthreads();

  // pass 1: local histogram; cache dst in registers for pass 2
  int dreg[EPE];
#pragma unroll
  for (int k = 0; k < EPE; ++k) {
    int i = e0 + k * BT_TPB + t;
    dreg[k] = -1;
    if (i < eEnd) {
      int d = dst[i];
      dreg[k] = d;
      atomicAdd(&B[d >> 6], 1);
    }
  }
  __syncthreads();

  // exclusive scan of B -> A via wave shuffles
  {
    const int EPT = 4;  // 512*4 = 2048 >= NB_MAX
    int b0 = t * EPT;
    int v[EPT];
    int sum = 0;
#pragma unroll
    for (int j = 0; j < EPT; ++j) {
      v[j] = (b0 + j < nB) ? B[b0 + j] : 0;
      sum += v[j];
    }
    int x = sum;
#pragma unroll
    for (int d = 1; d < 64; d <<= 1) {
      int y = __shfl_up(x, d, 64);
      if (lane >= d) x += y;
    }
    if (lane == 63) waveSums[wvid] = x;
    __syncthreads();
    int wprefix = 0;
    for (int i = 0; i < wvid; ++i) wprefix += waveSums[i];
    int run = wprefix + x - sum;
#pragma unroll
    for (int j = 0; j < EPT; ++j) {
      if (b0 + j < nB) A[b0 + j] = run;
      run += v[j];
    }
  }
  __syncthreads();

  // reserve global ranges; B becomes staging cursor, A becomes write delta
  for (int i = t; i < nB; i += BT_TPB) {
    int c = B[i];
    int l = A[i];
    int g = c ? atomicAdd(&gCursor[i], c) : 0;
    A[i] = i * CAP + g - l;
    B[i] = l;
  }
  __syncthreads();

  // pass 2: stage rec32 bucket-sorted (src/ew/em coalesced; dst from regs)
#pragma unroll
  for (int k = 0; k < EPE; ++k) {
    int i = e0 + k * BT_TPB + t;
    if (i < eEnd) {
      int d = dreg[k];
      int r = atomicAdd(&B[d >> 6], 1);
      float w = ew[i] * em[i];
      int wq = (int)(w * 511.0f + 0.5f);
      if (wq > 511) wq = 511;
      stage[r] = (unsigned)src[i] | ((unsigned)(d & 63) << 17) |
                 ((unsigned)wq << 23);
    }
  }
  __syncthreads();
  // B[j] now = loff[j+1]: monotone bucket END positions.

  // pass 3: coalesced write-out; bucket of i via binary search in LDS
  for (int i = t; i < nLocal; i += BT_TPB) {
    int lo = 0, hi = nB;
    while (lo < hi) {
      int mid = (lo + hi) >> 1;
      if (B[mid] > i) hi = mid; else lo = mid + 1;
    }
    int pos = A[lo] + i;
    if (pos < (lo + 1) * CAP)  // capacity guard (never fires statistically)
      recs[pos] = stage[i];
  }

  // feat -> bf16 AND fp8 (one read, two writes; grid-stride tail work)
  for (int c = blockIdx.x * BT_TPB + t; c < nChunks; c += gridDim.x * BT_TPB) {
    const float4* fp = reinterpret_cast<const float4*>(feat) + (size_t)c * 2;
    float4 a = fp[0], b = fp[1];
    uint4 o;
    o.x = pack2(a.x, a.y);
    o.y = pack2(a.z, a.w);
    o.z = pack2(b.x, b.y);
    o.w = pack2(b.z, b.w);
    reinterpret_cast<uint4*>(featb)[c] = o;
    uint2 q8;
    q8.x = pack_fp8x4(a.x, a.y, a.z, a.w);
    q8.y = pack_fp8x4(b.x, b.y, b.z, b.w);
    reinterpret_cast<uint2*>(featq)[c] = q8;
  }

  // W -> bf16 j-major block (block 0 only)
  if (blockIdx.x == 0) {
    for (int i = t; i < 1024; i += BT_TPB) {
      int j = i >> 4, c4 = i & 15;
      float4 w4 = reinterpret_cast<const float4*>(Ws)[i];
      float4 n4 = reinterpret_cast<const float4*>(Wn)[i];
      *reinterpret_cast<uint2*>(&Wb[j * 128 + c4 * 4]) =
          make_uint2(pack2(w4.x, w4.y), pack2(w4.z, w4.w));
      *reinterpret_cast<uint2*>(&Wb[j * 128 + 64 + c4 * 4]) =
          make_uint2(pack2(n4.x, n4.y), pack2(n4.z, n4.w));
    }
  }
}

// ---------------------------------------------------------------------------
// Fused gather + dual-linear.  Block = bucket = 64 dst nodes.
//   recs read ONCE coalesced into LDS; histogram + permute purely in LDS.
//   Gather: 4 lanes/node, fp8 feat row = ONE uint4 per lane per edge,
//   depth-2 prefetch, register accumulation.  MFMA as round 10.
// LDS ~ 18.5 KB.
// ---------------------------------------------------------------------------
__global__ __launch_bounds__(256) void sage_gather_gemm(
    const unsigned short* __restrict__ featb,
    const unsigned char* __restrict__ featq,
    const unsigned short* __restrict__ Wb, const int* __restrict__ gCursor,
    const unsigned* __restrict__ recs, const float* __restrict__ bs,
    const float* __restrict__ bn, float* __restrict__ out, int N) {
  __shared__ unsigned short An[64][72];  // h_neigh bf16; stride 72
  __shared__ unsigned rawL[CAP];         // 4 KB
  __shared__ unsigned srtL[CAP];         // 4 KB
  __shared__ int cntS[64], offS[64], curS[64];

  const int t = threadIdx.x;
  const int b = blockIdx.x;
  const int n0 = b * 64;
  const int base = b * CAP;
  const int cb = min(gCursor[b], CAP);

  // single coalesced global read of the bucket's records
  for (int i = t; i < cb; i += 256) rawL[i] = recs[base + i];
  if (t < 64) cntS[t] = 0;
  __syncthreads();

  // histogram by local node (LDS only)
  for (int i = t; i < cb; i += 256)
    atomicAdd(&cntS[(rawL[i] >> 17) & 63], 1);
  __syncthreads();

  // exclusive scan of 64 counters: wave-0 shuffle scan
  if (t < 64) {
    int c = cntS[t];
    int x = c;
#pragma unroll
    for (int d = 1; d < 64; d <<= 1) {
      int y = __shfl_up(x, d, 64);
      if (t >= d) x += y;
    }
    offS[t] = x - c;
    curS[t] = x - c;
  }
  __syncthreads();

  // permute into node-sorted order (LDS -> LDS)
  for (int i = t; i < cb; i += 256) {
    unsigned r = rawL[i];
    int p = atomicAdd(&curS[(r >> 17) & 63], 1);
    srtL[p] = r;
  }
  __syncthreads();

  // per-node gather: 4 lanes/node, one uint4 fp8 load per edge, depth-2 pipe
  {
    int nl = t >> 2, q = t & 3;
    int deg = cntS[nl], off = offS[nl];
    float acc[16];
#pragma unroll
    for (int i = 0; i < 16; ++i) acc[i] = 0.f;
    const uint4* fq = reinterpret_cast<const uint4*>(featq);  // row = 4 uint4

    uint4 uC, uN;
    float wC = 0.f, wN = 0.f;
    if (deg > 0) {
      unsigned r0 = srtL[off];
      uC = fq[(size_t)(r0 & 0x1FFFF) * 4 + q];
      wC = (float)(r0 >> 23) * (1.0f / 511.0f);
    }
    if (deg > 1) {
      unsigned r1 = srtL[off + 1];
      uN = fq[(size_t)(r1 & 0x1FFFF) * 4 + q];
      wN = (float)(r1 >> 23) * (1.0f / 511.0f);
    }
    for (int j = 0; j < deg; ++j) {
      uint4 u = uC;
      float w = wC;
      uC = uN; wC = wN;
      if (j + 2 < deg) {
        unsigned rn = srtL[off + j + 2];
        uN = fq[(size_t)(rn & 0x1FFFF) * 4 + q];
        wN = (float)(rn >> 23) * (1.0f / 511.0f);
      }
      dec4(acc + 0, u.x, w);
      dec4(acc + 4, u.y, w);
      dec4(acc + 8, u.z, w);
      dec4(acc + 12, u.w, w);
    }
    float inv = 1.0f / fmaxf((float)deg, 1.0f);
    uint4 o0, o1;
    o0.x = pack2(acc[0] * inv, acc[1] * inv);
    o0.y = pack2(acc[2] * inv, acc[3] * inv);
    o0.z = pack2(acc[4] * inv, acc[5] * inv);
    o0.w = pack2(acc[6] * inv, acc[7] * inv);
    o1.x = pack2(acc[8] * inv, acc[9] * inv);
    o1.y = pack2(acc[10] * inv, acc[11] * inv);
    o1.z = pack2(acc[12] * inv, acc[13] * inv);
    o1.w = pack2(acc[14] * inv, acc[15] * inv);
    *reinterpret_cast<uint4*>(&An[nl][q * 16]) = o0;
    *reinterpret_cast<uint4*>(&An[nl][q * 16 + 8]) = o1;
  }
  __syncthreads();

  // MFMA phase (round-4-validated mapping)
  const int wv = t >> 6;
  const int ln = t & 63;
  const int col = ln & 15;
  const int quad = ln >> 4;
  const int gn = n0 + wv * 16 + col;

  floatx4 acc4[4];
#pragma unroll
  for (int jt = 0; jt < 4; ++jt) {
    float bb = bs[jt * 16 + col] + bn[jt * 16 + col];
    acc4[jt] = (floatx4){bb, bb, bb, bb};
  }

#pragma unroll
  for (int kk = 0; kk < 4; ++kk) {
    bf16x8 af;
    if (kk < 2) {
      if (gn < N) {
        af = *reinterpret_cast<const bf16x8*>(featb + (size_t)gn * 64 + kk * 32 + quad * 8);
      } else {
        af = zero_bf16x8();
      }
    } else {
      af = *reinterpret_cast<const bf16x8*>(&An[wv * 16 + col][(kk - 2) * 32 + quad * 8]);
    }
#pragma unroll
    for (int jt = 0; jt < 4; ++jt) {
      bf16x8 bf = *reinterpret_cast<const bf16x8*>(
          Wb + (jt * 16 + col) * 128 + kk * 32 + quad * 8);
      acc4[jt] = __builtin_amdgcn_mfma_f32_16x16x32_bf16(af, bf, acc4[jt], 0, 0, 0);
    }
  }

#pragma unroll
  for (int jt = 0; jt < 4; ++jt) {
#pragma unroll
    for (int r = 0; r < 4; ++r) {
      int m = quad * 4 + r;
      int g = n0 + wv * 16 + m;
      if (g < N) out[(size_t)g * 64 + jt * 16 + col] = acc4[jt][r];
    }
  }
}

extern "C" void kernel_launch(void* const* d_in, const int* in_sizes, int n_in,
                              void* d_out, int out_size, void* d_ws, size_t ws_size,
                              hipStream_t stream) {
  const float* feat = (const float*)d_in[0];
  const int*   src  = (const int*)d_in[1];
  const int*   dst  = (const int*)d_in[2];
  const float* ew   = (const float*)d_in[3];
  const float* em   = (const float*)d_in[4];
  const float* Ws   = (const float*)d_in[5];
  const float* bs   = (const float*)d_in[6];
  const float* Wn   = (const float*)d_in[7];
  const float* bn   = (const float*)d_in[8];
  float* out = (float*)d_out;

  const int N = in_sizes[0] / 64;  // 100000
  const int E = in_sizes[1];       // 1200000
  const int nB = (N + 63) / 64;    // 1563

  // Workspace: featb 12.8MB | featq 6.4MB | Wb 16KB | recs 6.4MB | gCursor
  unsigned short* featb = (unsigned short*)d_ws;
  unsigned char*  featq = (unsigned char*)(featb + (size_t)N * 64);
  unsigned short* Wb    = (unsigned short*)(featq + (size_t)N * 64);
  unsigned* recs   = (unsigned*)(Wb + 64 * 128);
  int*      gCursor = (int*)(recs + (size_t)NB_MAX * CAP);

  hipMemsetAsync(gCursor, 0, NB_MAX * sizeof(int), stream);

  int nChunks = N * 8;  // 8-float conversion chunks
  int gB = (E + BT_EDGES - 1) / BT_EDGES;  // 293

  k_build<<<gB, BT_TPB, 0, stream>>>(feat, src, dst, ew, em, Ws, Wn,
                                     gCursor, recs, featb, featq, Wb,
                                     E, nChunks, nB);
  sage_gather_gemm<<<nB, 256, 0, stream>>>(featb, featq, Wb, gCursor, recs,
                                           bs, bn, out, N);
}

// Round 13
// 161.984 us; speedup vs baseline: 1.0355x; 1.0115x over previous
//
#include <hip/hip_runtime.h>

#define NB_MAX   1568   // buckets: ceil(100000/64)=1563, padded
#define CAP      1024   // fixed per-bucket record capacity (mean 768, +9σ safe)
#define BT_EDGES 4096   // edges per build tile
#define BT_TPB   512
#define EPE      8      // edges per thread in build (4096/512)

typedef __attribute__((ext_vector_type(4))) float floatx4;
typedef __attribute__((ext_vector_type(2))) float floatx2;
typedef __attribute__((ext_vector_type(8))) short bf16x8;

__device__ __forceinline__ unsigned short f32_to_bf16(float f) {
  unsigned u = __float_as_uint(f);
  u = (u + 0x7fffu + ((u >> 16) & 1u)) >> 16;  // RNE
  return (unsigned short)u;
}
__device__ __forceinline__ unsigned pack2(float a, float b) {
  return (unsigned)f32_to_bf16(a) | ((unsigned)f32_to_bf16(b) << 16);
}
__device__ __forceinline__ bf16x8 zero_bf16x8() {
  bf16x8 v;
#pragma unroll
  for (int i = 0; i < 8; ++i) v[i] = 0;
  return v;
}

// ---- fp8 e4m3fn helpers (HW path on gfx950; software fallback) ------------
#if __has_builtin(__builtin_amdgcn_cvt_pk_fp8_f32)
__device__ __forceinline__ unsigned pack_fp8x4(float a, float b, float c, float d) {
  unsigned v = (unsigned)__builtin_amdgcn_cvt_pk_fp8_f32(a, b, 0, false);
  v = (unsigned)__builtin_amdgcn_cvt_pk_fp8_f32(c, d, (int)v, true);
  return v;
}
#else
__device__ __forceinline__ unsigned sw_f32_fp8(float f) {
  unsigned u = __float_as_uint(f);
  unsigned s = (u >> 24) & 0x80u;
  unsigned au = u & 0x7fffffffu;
  if (au > 0x43E00000u) au = 0x43E00000u;      // clamp to 448
  au += 0x7FFFFu + ((au >> 20) & 1u);          // RNE at bit 20
  int e = (int)(au >> 23) - 120;               // fp8 exponent
  if (e <= 0) return s;                        // flush underflow to ±0
  return s | ((unsigned)e << 3) | ((au >> 20) & 7u);
}
__device__ __forceinline__ unsigned pack_fp8x4(float a, float b, float c, float d) {
  return sw_f32_fp8(a) | (sw_f32_fp8(b) << 8) | (sw_f32_fp8(c) << 16) |
         (sw_f32_fp8(d) << 24);
}
#endif

#if __has_builtin(__builtin_amdgcn_cvt_pk_f32_fp8)
__device__ __forceinline__ void dec4(float* acc, unsigned w32, float wt) {
  floatx2 f0 = __builtin_amdgcn_cvt_pk_f32_fp8((int)w32, false);
  floatx2 f1 = __builtin_amdgcn_cvt_pk_f32_fp8((int)w32, true);
  acc[0] += wt * f0.x; acc[1] += wt * f0.y;
  acc[2] += wt * f1.x; acc[3] += wt * f1.y;
}
#else
__device__ __forceinline__ float sw_fp8_f32(unsigned b) {
  unsigned s = (b & 0x80u) << 24;
  unsigned e = (b >> 3) & 0xFu;
  unsigned m = b & 7u;
  float fn = __uint_as_float(s | ((e + 120u) << 23) | (m << 20));
  float fd = (float)(int)m * 0.001953125f;      // 2^-9
  fd = (b & 0x80u) ? -fd : fd;
  return e ? fn : fd;
}
__device__ __forceinline__ void dec4(float* acc, unsigned w32, float wt) {
  acc[0] += wt * sw_fp8_f32(w32 & 0xFF);
  acc[1] += wt * sw_fp8_f32((w32 >> 8) & 0xFF);
  acc[2] += wt * sw_fp8_f32((w32 >> 16) & 0xFF);
  acc[3] += wt * sw_fp8_f32(w32 >> 24);
}
#endif

// ---------------------------------------------------------------------------
// Single-pass build (r12 verbatim — known-good).
// Record (32-bit): src(0..16) | dL(17..22) | w9(23..31).
// ---------------------------------------------------------------------------
__global__ __launch_bounds__(BT_TPB) void k_build(
    const float* __restrict__ feat, const int* __restrict__ src,
    const int* __restrict__ dst, const float* __restrict__ ew,
    const float* __restrict__ em, const float* __restrict__ Ws,
    const float* __restrict__ Wn, int* __restrict__ gCursor,
    unsigned* __restrict__ recs, unsigned short* __restrict__ featb,
    unsigned char* __restrict__ featq, unsigned short* __restrict__ Wb,
    int E, int nChunks, int nB) {
  __shared__ unsigned stage[BT_EDGES];  // 16 KB: bucket-sorted rec32
  __shared__ int A[NB_MAX];             // loff -> writebase-loff
  __shared__ int B[NB_MAX];             // cnt -> cursor -> ends
  __shared__ int waveSums[8];

  const int t = threadIdx.x;
  const int lane = t & 63;
  const int wvid = t >> 6;
  const int e0 = blockIdx.x * BT_EDGES;
  const int eEnd = min(e0 + BT_EDGES, E);
  const int nLocal = eEnd - e0;

  for (int i = t; i < NB_MAX; i += BT_TPB) B[i] = 0;
  __syncthreads();

  // pass 1: local histogram; cache dst in registers for pass 2
  int dreg[EPE];
#pragma unroll
  for (int k = 0; k < EPE; ++k) {
    int i = e0 + k * BT_TPB + t;
    dreg[k] = -1;
    if (i < eEnd) {
      int d = dst[i];
      dreg[k] = d;
      atomicAdd(&B[d >> 6], 1);
    }
  }
  __syncthreads();

  // exclusive scan of B -> A via wave shuffles
  {
    const int EPT = 4;  // 512*4 = 2048 >= NB_MAX
    int b0 = t * EPT;
    int v[EPT];
    int sum = 0;
#pragma unroll
    for (int j = 0; j < EPT; ++j) {
      v[j] = (b0 + j < nB) ? B[b0 + j] : 0;
      sum += v[j];
    }
    int x = sum;
#pragma unroll
    for (int d = 1; d < 64; d <<= 1) {
      int y = __shfl_up(x, d, 64);
      if (lane >= d) x += y;
    }
    if (lane == 63) waveSums[wvid] = x;
    __syncthreads();
    int wprefix = 0;
    for (int i = 0; i < wvid; ++i) wprefix += waveSums[i];
    int run = wprefix + x - sum;
#pragma unroll
    for (int j = 0; j < EPT; ++j) {
      if (b0 + j < nB) A[b0 + j] = run;
      run += v[j];
    }
  }
  __syncthreads();

  // reserve global ranges; B becomes staging cursor, A becomes write delta
  for (int i = t; i < nB; i += BT_TPB) {
    int c = B[i];
    int l = A[i];
    int g = c ? atomicAdd(&gCursor[i], c) : 0;
    A[i] = i * CAP + g - l;
    B[i] = l;
  }
  __syncthreads();

  // pass 2: stage rec32 bucket-sorted (src/ew/em coalesced; dst from regs)
#pragma unroll
  for (int k = 0; k < EPE; ++k) {
    int i = e0 + k * BT_TPB + t;
    if (i < eEnd) {
      int d = dreg[k];
      int r = atomicAdd(&B[d >> 6], 1);
      float w = ew[i] * em[i];
      int wq = (int)(w * 511.0f + 0.5f);
      if (wq > 511) wq = 511;
      stage[r] = (unsigned)src[i] | ((unsigned)(d & 63) << 17) |
                 ((unsigned)wq << 23);
    }
  }
  __syncthreads();
  // B[j] now = loff[j+1]: monotone bucket END positions.

  // pass 3: coalesced write-out; bucket of i via binary search in LDS
  for (int i = t; i < nLocal; i += BT_TPB) {
    int lo = 0, hi = nB;
    while (lo < hi) {
      int mid = (lo + hi) >> 1;
      if (B[mid] > i) hi = mid; else lo = mid + 1;
    }
    int pos = A[lo] + i;
    if (pos < (lo + 1) * CAP)  // capacity guard (never fires statistically)
      recs[pos] = stage[i];
  }

  // feat -> bf16 AND fp8 (one read, two writes; grid-stride tail work)
  for (int c = blockIdx.x * BT_TPB + t; c < nChunks; c += gridDim.x * BT_TPB) {
    const float4* fp = reinterpret_cast<const float4*>(feat) + (size_t)c * 2;
    float4 a = fp[0], b = fp[1];
    uint4 o;
    o.x = pack2(a.x, a.y);
    o.y = pack2(a.z, a.w);
    o.z = pack2(b.x, b.y);
    o.w = pack2(b.z, b.w);
    reinterpret_cast<uint4*>(featb)[c] = o;
    uint2 q8;
    q8.x = pack_fp8x4(a.x, a.y, a.z, a.w);
    q8.y = pack_fp8x4(b.x, b.y, b.z, b.w);
    reinterpret_cast<uint2*>(featq)[c] = q8;
  }

  // W -> bf16 j-major block (block 0 only)
  if (blockIdx.x == 0) {
    for (int i = t; i < 1024; i += BT_TPB) {
      int j = i >> 4, c4 = i & 15;
      float4 w4 = reinterpret_cast<const float4*>(Ws)[i];
      float4 n4 = reinterpret_cast<const float4*>(Wn)[i];
      *reinterpret_cast<uint2*>(&Wb[j * 128 + c4 * 4]) =
          make_uint2(pack2(w4.x, w4.y), pack2(w4.z, w4.w));
      *reinterpret_cast<uint2*>(&Wb[j * 128 + 64 + c4 * 4]) =
          make_uint2(pack2(n4.x, n4.y), pack2(n4.z, n4.w));
    }
  }
}

// ---------------------------------------------------------------------------
// Fused gather + dual-linear (v2): 512 threads, 8 lanes/node = 2 edge-parity
// groups x 4 dim-quads.  Each group accumulates the full 64-dim fp8 row over
// HALF the node's edges (stride 2 through sorted records) -> critical path
// ~max_deg/2; 2 groups x depth-2 prefetch = 4 loads in flight per node.
// Groups combine via f32 LDS partials.  MFMA split over 8 waves
// (4 node-tiles x 2 j-halves, 8 MFMA each).  LDS ~34.5 KB.
// ---------------------------------------------------------------------------
__global__ __launch_bounds__(512) void sage_gather_gemm(
    const unsigned short* __restrict__ featb,
    const unsigned char* __restrict__ featq,
    const unsigned short* __restrict__ Wb, const int* __restrict__ gCursor,
    const unsigned* __restrict__ recs, const float* __restrict__ bs,
    const float* __restrict__ bn, float* __restrict__ out, int N) {
  __shared__ unsigned short An[64][72];  // h_neigh bf16; stride 72
  __shared__ unsigned rawL[CAP];         // 4 KB
  __shared__ unsigned srtL[CAP];         // 4 KB
  __shared__ float pf[64][64];           // 16 KB: group-1 partial sums
  __shared__ int cntS[64], offS[64], curS[64];

  const int t = threadIdx.x;
  const int b = blockIdx.x;
  const int n0 = b * 64;
  const int base = b * CAP;
  const int cb = min(gCursor[b], CAP);

  // single coalesced global read of the bucket's records
  for (int i = t; i < cb; i += 512) rawL[i] = recs[base + i];
  if (t < 64) cntS[t] = 0;
  __syncthreads();

  // histogram by local node (LDS only)
  for (int i = t; i < cb; i += 512)
    atomicAdd(&cntS[(rawL[i] >> 17) & 63], 1);
  __syncthreads();

  // exclusive scan of 64 counters: wave-0 shuffle scan
  if (t < 64) {
    int c = cntS[t];
    int x = c;
#pragma unroll
    for (int d = 1; d < 64; d <<= 1) {
      int y = __shfl_up(x, d, 64);
      if (t >= d) x += y;
    }
    offS[t] = x - c;
    curS[t] = x - c;
  }
  __syncthreads();

  // permute into node-sorted order (LDS -> LDS)
  for (int i = t; i < cb; i += 512) {
    unsigned r = rawL[i];
    int p = atomicAdd(&curS[(r >> 17) & 63], 1);
    srtL[p] = r;
  }
  __syncthreads();

  // per-node gather: 8 lanes/node (2 edge-parity groups x 4 dim-quads)
  {
    const int nl = t >> 3;        // local node 0..63
    const int g  = (t >> 2) & 1;  // edge-parity group
    const int q  = t & 3;         // 16-dim chunk
    const int deg = cntS[nl], off = offS[nl];
    const int myN = (deg - g + 1) >> 1;  // #edges this group handles
    float acc[16];
#pragma unroll
    for (int i = 0; i < 16; ++i) acc[i] = 0.f;
    const uint4* fq = reinterpret_cast<const uint4*>(featq);  // row = 4 uint4

    uint4 uC, uN;
    float wC = 0.f, wN = 0.f;
    if (myN > 0) {
      unsigned r0 = srtL[off + g];
      uC = fq[(size_t)(r0 & 0x1FFFF) * 4 + q];
      wC = (float)(r0 >> 23) * (1.0f / 511.0f);
    }
    if (myN > 1) {
      unsigned r1 = srtL[off + g + 2];
      uN = fq[(size_t)(r1 & 0x1FFFF) * 4 + q];
      wN = (float)(r1 >> 23) * (1.0f / 511.0f);
    }
    for (int m = 0; m < myN; ++m) {
      uint4 u = uC;
      float w = wC;
      uC = uN; wC = wN;
      if (m + 2 < myN) {
        unsigned rn = srtL[off + g + 2 * (m + 2)];
        uN = fq[(size_t)(rn & 0x1FFFF) * 4 + q];
        wN = (float)(rn >> 23) * (1.0f / 511.0f);
      }
      dec4(acc + 0, u.x, w);
      dec4(acc + 4, u.y, w);
      dec4(acc + 8, u.z, w);
      dec4(acc + 12, u.w, w);
    }

    // combine: group 1 publishes partials; group 0 adds, normalizes, packs
    if (g == 1) {
#pragma unroll
      for (int i = 0; i < 16; ++i) pf[nl][q * 16 + i] = acc[i];
    }
    __syncthreads();
    if (g == 0) {
      float inv = 1.0f / fmaxf((float)deg, 1.0f);
#pragma unroll
      for (int i = 0; i < 16; ++i) acc[i] = (acc[i] + pf[nl][q * 16 + i]) * inv;
      uint4 o0, o1;
      o0.x = pack2(acc[0], acc[1]);
      o0.y = pack2(acc[2], acc[3]);
      o0.z = pack2(acc[4], acc[5]);
      o0.w = pack2(acc[6], acc[7]);
      o1.x = pack2(acc[8], acc[9]);
      o1.y = pack2(acc[10], acc[11]);
      o1.z = pack2(acc[12], acc[13]);
      o1.w = pack2(acc[14], acc[15]);
      *reinterpret_cast<uint4*>(&An[nl][q * 16]) = o0;
      *reinterpret_cast<uint4*>(&An[nl][q * 16 + 8]) = o1;
    }
  }
  __syncthreads();

  // MFMA phase: 8 waves = 4 node-tiles x 2 j-halves (round-4 lane mapping)
  const int wv8 = t >> 6;       // 0..7
  const int nt = wv8 & 3;       // node tile (16 nodes)
  const int jh = wv8 >> 2;      // j-half: jt in {jh*2, jh*2+1}
  const int ln = t & 63;
  const int col = ln & 15;
  const int quad = ln >> 4;
  const int gn = n0 + nt * 16 + col;

  floatx4 acc4[2];
#pragma unroll
  for (int jj = 0; jj < 2; ++jj) {
    int jt = jh * 2 + jj;
    float bb = bs[jt * 16 + col] + bn[jt * 16 + col];
    acc4[jj] = (floatx4){bb, bb, bb, bb};
  }

#pragma unroll
  for (int kk = 0; kk < 4; ++kk) {
    bf16x8 af;
    if (kk < 2) {
      if (gn < N) {
        af = *reinterpret_cast<const bf16x8*>(featb + (size_t)gn * 64 + kk * 32 + quad * 8);
      } else {
        af = zero_bf16x8();
      }
    } else {
      af = *reinterpret_cast<const bf16x8*>(&An[nt * 16 + col][(kk - 2) * 32 + quad * 8]);
    }
#pragma unroll
    for (int jj = 0; jj < 2; ++jj) {
      int jt = jh * 2 + jj;
      bf16x8 bf = *reinterpret_cast<const bf16x8*>(
          Wb + (jt * 16 + col) * 128 + kk * 32 + quad * 8);
      acc4[jj] = __builtin_amdgcn_mfma_f32_16x16x32_bf16(af, bf, acc4[jj], 0, 0, 0);
    }
  }

#pragma unroll
  for (int jj = 0; jj < 2; ++jj) {
    int jt = jh * 2 + jj;
#pragma unroll
    for (int r = 0; r < 4; ++r) {
      int m = quad * 4 + r;
      int g2 = n0 + nt * 16 + m;
      if (g2 < N) out[(size_t)g2 * 64 + jt * 16 + col] = acc4[jj][r];
    }
  }
}

extern "C" void kernel_launch(void* const* d_in, const int* in_sizes, int n_in,
                              void* d_out, int out_size, void* d_ws, size_t ws_size,
                              hipStream_t stream) {
  const float* feat = (const float*)d_in[0];
  const int*   src  = (const int*)d_in[1];
  const int*   dst  = (const int*)d_in[2];
  const float* ew   = (const float*)d_in[3];
  const float* em   = (const float*)d_in[4];
  const float* Ws   = (const float*)d_in[5];
  const float* bs   = (const float*)d_in[6];
  const float* Wn   = (const float*)d_in[7];
  const float* bn   = (const float*)d_in[8];
  float* out = (float*)d_out;

  const int N = in_sizes[0] / 64;  // 100000
  const int E = in_sizes[1];       // 1200000
  const int nB = (N + 63) / 64;    // 1563

  // Workspace: featb 12.8MB | featq 6.4MB | Wb 16KB | recs 6.4MB | gCursor
  unsigned short* featb = (unsigned short*)d_ws;
  unsigned char*  featq = (unsigned char*)(featb + (size_t)N * 64);
  unsigned short* Wb    = (unsigned short*)(featq + (size_t)N * 64);
  unsigned* recs   = (unsigned*)(Wb + 64 * 128);
  int*      gCursor = (int*)(recs + (size_t)NB_MAX * CAP);

  hipMemsetAsync(gCursor, 0, NB_MAX * sizeof(int), stream);

  int nChunks = N * 8;  // 8-float conversion chunks
  int gB = (E + BT_EDGES - 1) / BT_EDGES;  // 293

  k_build<<<gB, BT_TPB, 0, stream>>>(feat, src, dst, ew, em, Ws, Wn,
                                     gCursor, recs, featb, featq, Wb,
                                     E, nChunks, nB);
  sage_gather_gemm<<<nB, 512, 0, stream>>>(featb, featq, Wb, gCursor, recs,
                                           bs, bn, out, N);
}

// Round 14
// 161.246 us; speedup vs baseline: 1.0402x; 1.0046x over previous
//
#include <hip/hip_runtime.h>

#define NB_MAX   1568   // buckets: ceil(100000/64)=1563, padded
#define CAP      1024   // fixed per-bucket record capacity (mean 768, +9σ safe)
#define BT_EDGES 4096   // edges per build tile
#define BT_TPB   1024
#define EPE      4      // edges per thread in build (4096/1024)

typedef __attribute__((ext_vector_type(4))) float floatx4;
typedef __attribute__((ext_vector_type(2))) float floatx2;
typedef __attribute__((ext_vector_type(8))) short bf16x8;

__device__ __forceinline__ unsigned short f32_to_bf16(float f) {
  unsigned u = __float_as_uint(f);
  u = (u + 0x7fffu + ((u >> 16) & 1u)) >> 16;  // RNE
  return (unsigned short)u;
}
__device__ __forceinline__ unsigned pack2(float a, float b) {
  return (unsigned)f32_to_bf16(a) | ((unsigned)f32_to_bf16(b) << 16);
}
__device__ __forceinline__ bf16x8 zero_bf16x8() {
  bf16x8 v;
#pragma unroll
  for (int i = 0; i < 8; ++i) v[i] = 0;
  return v;
}

// ---- fp8 e4m3fn helpers (HW path on gfx950; software fallback) ------------
#if __has_builtin(__builtin_amdgcn_cvt_pk_fp8_f32)
__device__ __forceinline__ unsigned pack_fp8x4(float a, float b, float c, float d) {
  unsigned v = (unsigned)__builtin_amdgcn_cvt_pk_fp8_f32(a, b, 0, false);
  v = (unsigned)__builtin_amdgcn_cvt_pk_fp8_f32(c, d, (int)v, true);
  return v;
}
#else
__device__ __forceinline__ unsigned sw_f32_fp8(float f) {
  unsigned u = __float_as_uint(f);
  unsigned s = (u >> 24) & 0x80u;
  unsigned au = u & 0x7fffffffu;
  if (au > 0x43E00000u) au = 0x43E00000u;      // clamp to 448
  au += 0x7FFFFu + ((au >> 20) & 1u);          // RNE at bit 20
  int e = (int)(au >> 23) - 120;               // fp8 exponent
  if (e <= 0) return s;                        // flush underflow to ±0
  return s | ((unsigned)e << 3) | ((au >> 20) & 7u);
}
__device__ __forceinline__ unsigned pack_fp8x4(float a, float b, float c, float d) {
  return sw_f32_fp8(a) | (sw_f32_fp8(b) << 8) | (sw_f32_fp8(c) << 16) |
         (sw_f32_fp8(d) << 24);
}
#endif

#if __has_builtin(__builtin_amdgcn_cvt_pk_f32_fp8)
__device__ __forceinline__ void dec4(float* acc, unsigned w32, float wt) {
  floatx2 f0 = __builtin_amdgcn_cvt_pk_f32_fp8((int)w32, false);
  floatx2 f1 = __builtin_amdgcn_cvt_pk_f32_fp8((int)w32, true);
  acc[0] += wt * f0.x; acc[1] += wt * f0.y;
  acc[2] += wt * f1.x; acc[3] += wt * f1.y;
}
#else
__device__ __forceinline__ float sw_fp8_f32(unsigned b) {
  unsigned s = (b & 0x80u) << 24;
  unsigned e = (b >> 3) & 0xFu;
  unsigned m = b & 7u;
  float fn = __uint_as_float(s | ((e + 120u) << 23) | (m << 20));
  float fd = (float)(int)m * 0.001953125f;      // 2^-9
  fd = (b & 0x80u) ? -fd : fd;
  return e ? fn : fd;
}
__device__ __forceinline__ void dec4(float* acc, unsigned w32, float wt) {
  acc[0] += wt * sw_fp8_f32(w32 & 0xFF);
  acc[1] += wt * sw_fp8_f32((w32 >> 8) & 0xFF);
  acc[2] += wt * sw_fp8_f32((w32 >> 16) & 0xFF);
  acc[3] += wt * sw_fp8_f32(w32 >> 24);
}
#endif

// ---------------------------------------------------------------------------
// Single-pass build (v4): 1024 threads (16 waves -> ~2x wave pool around the
// barrier ladder) + stageB bucket-id array so pass 3 does a depth-2 LDS
// chain instead of an 11-deep binary-search pointer chase.
// Record (32-bit): src(0..16) | dL(17..22) | w9(23..31).
// LDS: stage 16K + stageB 8K + A/B 12.5K = 36.6 KB.
// ---------------------------------------------------------------------------
__global__ __launch_bounds__(BT_TPB) void k_build(
    const float* __restrict__ feat, const int* __restrict__ src,
    const int* __restrict__ dst, const float* __restrict__ ew,
    const float* __restrict__ em, const float* __restrict__ Ws,
    const float* __restrict__ Wn, int* __restrict__ gCursor,
    unsigned* __restrict__ recs, unsigned short* __restrict__ featb,
    unsigned char* __restrict__ featq, unsigned short* __restrict__ Wb,
    int E, int nChunks, int nB) {
  __shared__ unsigned stage[BT_EDGES];         // bucket-sorted rec32 (16 KB)
  __shared__ unsigned short stageB[BT_EDGES];  // bucket id per slot   (8 KB)
  __shared__ int A[NB_MAX];                    // loff -> writebase-loff
  __shared__ int B[NB_MAX];                    // cnt -> cursor -> ends
  __shared__ int waveSums[16];

  const int t = threadIdx.x;
  const int lane = t & 63;
  const int wvid = t >> 6;
  const int e0 = blockIdx.x * BT_EDGES;
  const int eEnd = min(e0 + BT_EDGES, E);
  const int nLocal = eEnd - e0;

  for (int i = t; i < NB_MAX; i += BT_TPB) B[i] = 0;
  __syncthreads();

  // pass 1: local histogram; cache dst in registers for pass 2
  int dreg[EPE];
#pragma unroll
  for (int k = 0; k < EPE; ++k) {
    int i = e0 + k * BT_TPB + t;
    dreg[k] = -1;
    if (i < eEnd) {
      int d = dst[i];
      dreg[k] = d;
      atomicAdd(&B[d >> 6], 1);
    }
  }
  __syncthreads();

  // exclusive scan of B -> A via wave shuffles (EPT=2, 1024*2=2048 >= NB_MAX)
  {
    const int EPT = 2;
    int b0 = t * EPT;
    int v[EPT];
    int sum = 0;
#pragma unroll
    for (int j = 0; j < EPT; ++j) {
      v[j] = (b0 + j < nB) ? B[b0 + j] : 0;
      sum += v[j];
    }
    int x = sum;
#pragma unroll
    for (int d = 1; d < 64; d <<= 1) {
      int y = __shfl_up(x, d, 64);
      if (lane >= d) x += y;
    }
    if (lane == 63) waveSums[wvid] = x;
    __syncthreads();
    int wprefix = 0;
    for (int i = 0; i < wvid; ++i) wprefix += waveSums[i];
    int run = wprefix + x - sum;
#pragma unroll
    for (int j = 0; j < EPT; ++j) {
      if (b0 + j < nB) A[b0 + j] = run;
      run += v[j];
    }
  }
  __syncthreads();

  // reserve global ranges; B becomes staging cursor, A becomes write delta
  for (int i = t; i < nB; i += BT_TPB) {
    int c = B[i];
    int l = A[i];
    int g = c ? atomicAdd(&gCursor[i], c) : 0;
    A[i] = i * CAP + g - l;
    B[i] = l;
  }
  __syncthreads();

  // pass 2: stage rec32 + bucket id, bucket-sorted
#pragma unroll
  for (int k = 0; k < EPE; ++k) {
    int i = e0 + k * BT_TPB + t;
    if (i < eEnd) {
      int d = dreg[k];
      int bkt = d >> 6;
      int r = atomicAdd(&B[bkt], 1);
      float w = ew[i] * em[i];
      int wq = (int)(w * 511.0f + 0.5f);
      if (wq > 511) wq = 511;
      stage[r] = (unsigned)src[i] | ((unsigned)(d & 63) << 17) |
                 ((unsigned)wq << 23);
      stageB[r] = (unsigned short)bkt;
    }
  }
  __syncthreads();

  // pass 3: coalesced write-out; bucket id read directly (depth-2 LDS chain)
  for (int i = t; i < nLocal; i += BT_TPB) {
    int bkt = stageB[i];
    int pos = A[bkt] + i;
    if (pos < (bkt + 1) * CAP)  // capacity guard (never fires statistically)
      recs[pos] = stage[i];
  }

  // feat -> bf16 AND fp8 (one read, two writes; grid-stride tail work)
  for (int c = blockIdx.x * BT_TPB + t; c < nChunks; c += gridDim.x * BT_TPB) {
    const float4* fp = reinterpret_cast<const float4*>(feat) + (size_t)c * 2;
    float4 a = fp[0], b = fp[1];
    uint4 o;
    o.x = pack2(a.x, a.y);
    o.y = pack2(a.z, a.w);
    o.z = pack2(b.x, b.y);
    o.w = pack2(b.z, b.w);
    reinterpret_cast<uint4*>(featb)[c] = o;
    uint2 q8;
    q8.x = pack_fp8x4(a.x, a.y, a.z, a.w);
    q8.y = pack_fp8x4(b.x, b.y, b.z, b.w);
    reinterpret_cast<uint2*>(featq)[c] = q8;
  }

  // W -> bf16 j-major block (block 0 only)
  if (blockIdx.x == 0) {
    for (int i = t; i < 1024; i += BT_TPB) {
      int j = i >> 4, c4 = i & 15;
      float4 w4 = reinterpret_cast<const float4*>(Ws)[i];
      float4 n4 = reinterpret_cast<const float4*>(Wn)[i];
      *reinterpret_cast<uint2*>(&Wb[j * 128 + c4 * 4]) =
          make_uint2(pack2(w4.x, w4.y), pack2(w4.z, w4.w));
      *reinterpret_cast<uint2*>(&Wb[j * 128 + 64 + c4 * 4]) =
          make_uint2(pack2(n4.x, n4.y), pack2(n4.z, n4.w));
    }
  }
}

// ---------------------------------------------------------------------------
// Fused gather + dual-linear (r13 verbatim): 512 threads, 8 lanes/node =
// 2 edge-parity groups x 4 dim-quads; fp8 rows; LDS-sorted records;
// MFMA split over 8 waves.  LDS ~34.5 KB.
// ---------------------------------------------------------------------------
__global__ __launch_bounds__(512) void sage_gather_gemm(
    const unsigned short* __restrict__ featb,
    const unsigned char* __restrict__ featq,
    const unsigned short* __restrict__ Wb, const int* __restrict__ gCursor,
    const unsigned* __restrict__ recs, const float* __restrict__ bs,
    const float* __restrict__ bn, float* __restrict__ out, int N) {
  __shared__ unsigned short An[64][72];  // h_neigh bf16; stride 72
  __shared__ unsigned rawL[CAP];         // 4 KB
  __shared__ unsigned srtL[CAP];         // 4 KB
  __shared__ float pf[64][64];           // 16 KB: group-1 partial sums
  __shared__ int cntS[64], offS[64], curS[64];

  const int t = threadIdx.x;
  const int b = blockIdx.x;
  const int n0 = b * 64;
  const int base = b * CAP;
  const int cb = min(gCursor[b], CAP);

  // single coalesced global read of the bucket's records
  for (int i = t; i < cb; i += 512) rawL[i] = recs[base + i];
  if (t < 64) cntS[t] = 0;
  __syncthreads();

  // histogram by local node (LDS only)
  for (int i = t; i < cb; i += 512)
    atomicAdd(&cntS[(rawL[i] >> 17) & 63], 1);
  __syncthreads();

  // exclusive scan of 64 counters: wave-0 shuffle scan
  if (t < 64) {
    int c = cntS[t];
    int x = c;
#pragma unroll
    for (int d = 1; d < 64; d <<= 1) {
      int y = __shfl_up(x, d, 64);
      if (t >= d) x += y;
    }
    offS[t] = x - c;
    curS[t] = x - c;
  }
  __syncthreads();

  // permute into node-sorted order (LDS -> LDS)
  for (int i = t; i < cb; i += 512) {
    unsigned r = rawL[i];
    int p = atomicAdd(&curS[(r >> 17) & 63], 1);
    srtL[p] = r;
  }
  __syncthreads();

  // per-node gather: 8 lanes/node (2 edge-parity groups x 4 dim-quads)
  {
    const int nl = t >> 3;        // local node 0..63
    const int g  = (t >> 2) & 1;  // edge-parity group
    const int q  = t & 3;         // 16-dim chunk
    const int deg = cntS[nl], off = offS[nl];
    const int myN = (deg - g + 1) >> 1;  // #edges this group handles
    float acc[16];
#pragma unroll
    for (int i = 0; i < 16; ++i) acc[i] = 0.f;
    const uint4* fq = reinterpret_cast<const uint4*>(featq);  // row = 4 uint4

    uint4 uC, uN;
    float wC = 0.f, wN = 0.f;
    if (myN > 0) {
      unsigned r0 = srtL[off + g];
      uC = fq[(size_t)(r0 & 0x1FFFF) * 4 + q];
      wC = (float)(r0 >> 23) * (1.0f / 511.0f);
    }
    if (myN > 1) {
      unsigned r1 = srtL[off + g + 2];
      uN = fq[(size_t)(r1 & 0x1FFFF) * 4 + q];
      wN = (float)(r1 >> 23) * (1.0f / 511.0f);
    }
    for (int m = 0; m < myN; ++m) {
      uint4 u = uC;
      float w = wC;
      uC = uN; wC = wN;
      if (m + 2 < myN) {
        unsigned rn = srtL[off + g + 2 * (m + 2)];
        uN = fq[(size_t)(rn & 0x1FFFF) * 4 + q];
        wN = (float)(rn >> 23) * (1.0f / 511.0f);
      }
      dec4(acc + 0, u.x, w);
      dec4(acc + 4, u.y, w);
      dec4(acc + 8, u.z, w);
      dec4(acc + 12, u.w, w);
    }

    // combine: group 1 publishes partials; group 0 adds, normalizes, packs
    if (g == 1) {
#pragma unroll
      for (int i = 0; i < 16; ++i) pf[nl][q * 16 + i] = acc[i];
    }
    __syncthreads();
    if (g == 0) {
      float inv = 1.0f / fmaxf((float)deg, 1.0f);
#pragma unroll
      for (int i = 0; i < 16; ++i) acc[i] = (acc[i] + pf[nl][q * 16 + i]) * inv;
      uint4 o0, o1;
      o0.x = pack2(acc[0], acc[1]);
      o0.y = pack2(acc[2], acc[3]);
      o0.z = pack2(acc[4], acc[5]);
      o0.w = pack2(acc[6], acc[7]);
      o1.x = pack2(acc[8], acc[9]);
      o1.y = pack2(acc[10], acc[11]);
      o1.z = pack2(acc[12], acc[13]);
      o1.w = pack2(acc[14], acc[15]);
      *reinterpret_cast<uint4*>(&An[nl][q * 16]) = o0;
      *reinterpret_cast<uint4*>(&An[nl][q * 16 + 8]) = o1;
    }
  }
  __syncthreads();

  // MFMA phase: 8 waves = 4 node-tiles x 2 j-halves (round-4 lane mapping)
  const int wv8 = t >> 6;       // 0..7
  const int nt = wv8 & 3;       // node tile (16 nodes)
  const int jh = wv8 >> 2;      // j-half: jt in {jh*2, jh*2+1}
  const int ln = t & 63;
  const int col = ln & 15;
  const int quad = ln >> 4;
  const int gn = n0 + nt * 16 + col;

  floatx4 acc4[2];
#pragma unroll
  for (int jj = 0; jj < 2; ++jj) {
    int jt = jh * 2 + jj;
    float bb = bs[jt * 16 + col] + bn[jt * 16 + col];
    acc4[jj] = (floatx4){bb, bb, bb, bb};
  }

#pragma unroll
  for (int kk = 0; kk < 4; ++kk) {
    bf16x8 af;
    if (kk < 2) {
      if (gn < N) {
        af = *reinterpret_cast<const bf16x8*>(featb + (size_t)gn * 64 + kk * 32 + quad * 8);
      } else {
        af = zero_bf16x8();
      }
    } else {
      af = *reinterpret_cast<const bf16x8*>(&An[nt * 16 + col][(kk - 2) * 32 + quad * 8]);
    }
#pragma unroll
    for (int jj = 0; jj < 2; ++jj) {
      int jt = jh * 2 + jj;
      bf16x8 bf = *reinterpret_cast<const bf16x8*>(
          Wb + (jt * 16 + col) * 128 + kk * 32 + quad * 8);
      acc4[jj] = __builtin_amdgcn_mfma_f32_16x16x32_bf16(af, bf, acc4[jj], 0, 0, 0);
    }
  }

#pragma unroll
  for (int jj = 0; jj < 2; ++jj) {
    int jt = jh * 2 + jj;
#pragma unroll
    for (int r = 0; r < 4; ++r) {
      int m = quad * 4 + r;
      int g2 = n0 + nt * 16 + m;
      if (g2 < N) out[(size_t)g2 * 64 + jt * 16 + col] = acc4[jj][r];
    }
  }
}

extern "C" void kernel_launch(void* const* d_in, const int* in_sizes, int n_in,
                              void* d_out, int out_size, void* d_ws, size_t ws_size,
                              hipStream_t stream) {
  const float* feat = (const float*)d_in[0];
  const int*   src  = (const int*)d_in[1];
  const int*   dst  = (const int*)d_in[2];
  const float* ew   = (const float*)d_in[3];
  const float* em   = (const float*)d_in[4];
  const float* Ws   = (const float*)d_in[5];
  const float* bs   = (const float*)d_in[6];
  const float* Wn   = (const float*)d_in[7];
  const float* bn   = (const float*)d_in[8];
  float* out = (float*)d_out;

  const int N = in_sizes[0] / 64;  // 100000
  const int E = in_sizes[1];       // 1200000
  const int nB = (N + 63) / 64;    // 1563

  // Workspace: featb 12.8MB | featq 6.4MB | Wb 16KB | recs 6.4MB | gCursor
  unsigned short* featb = (unsigned short*)d_ws;
  unsigned char*  featq = (unsigned char*)(featb + (size_t)N * 64);
  unsigned short* Wb    = (unsigned short*)(featq + (size_t)N * 64);
  unsigned* recs   = (unsigned*)(Wb + 64 * 128);
  int*      gCursor = (int*)(recs + (size_t)NB_MAX * CAP);

  hipMemsetAsync(gCursor, 0, NB_MAX * sizeof(int), stream);

  int nChunks = N * 8;  // 8-float conversion chunks
  int gB = (E + BT_EDGES - 1) / BT_EDGES;  // 293

  k_build<<<gB, BT_TPB, 0, stream>>>(feat, src, dst, ew, em, Ws, Wn,
                                     gCursor, recs, featb, featq, Wb,
                                     E, nChunks, nB);
  sage_gather_gemm<<<nB, 512, 0, stream>>>(featb, featq, Wb, gCursor, recs,
                                           bs, bn, out, N);
}